// Round 8
// baseline (207.614 us; speedup 1.0000x reference)
//
#include <hip/hip_runtime.h>
#include <hip/hip_bf16.h>

#define SEQ 2048
#define DIMM 2048
#define NQH 32
#define NKVH 8
#define HD 64

typedef _Float16 half8 __attribute__((ext_vector_type(8)));
typedef float f32x4 __attribute__((ext_vector_type(4)));
using fp16 = _Float16;

typedef __attribute__((address_space(1))) unsigned int ga_u32;
typedef __attribute__((address_space(3))) unsigned int ls_u32;

__device__ __forceinline__ void gll16(const void* g, void* l) {
    __builtin_amdgcn_global_load_lds((const ga_u32*)g, (ls_u32*)l, 16, 0, 0);
}

// ---------------- cast fp32 -> fp16 (vectorized) ----------------
__global__ void cast_f32_f16(const float* __restrict__ in, fp16* __restrict__ out, int n) {
    int i = (blockIdx.x * 256 + threadIdx.x) * 4;
    if (i < n) {
        float4 v = *reinterpret_cast<const float4*>(in + i);
#pragma unroll
        for (int j = 0; j < 4; j++) out[i + j] = (fp16)(&v.x)[j];
    }
}

// ------------- tiled transpose + cast: in fp32 [head][R][C] -> out fp16 [head][C][R] -------------
__global__ void transpose_cast(const float* __restrict__ in, fp16* __restrict__ out, int R, int C) {
    __shared__ float tile[64][65];
    const float* inh = in + (size_t)blockIdx.z * R * C;
    fp16* outh = out + (size_t)blockIdx.z * R * C;
    int r0 = blockIdx.x * 64, c0 = blockIdx.y * 64;
    int t = threadIdx.x;
#pragma unroll
    for (int i = 0; i < 16; i++) {
        int idx = i * 256 + t;
        int r = idx >> 6, c = idx & 63;
        tile[r][c] = inh[(size_t)(r0 + r) * C + c0 + c];
    }
    __syncthreads();
#pragma unroll
    for (int i = 0; i < 16; i++) {
        int idx = i * 256 + t;
        int cc = idx >> 6, rr = idx & 63;
        outh[(size_t)(c0 + cc) * R + r0 + rr] = (fp16)tile[rr][cc];
    }
}

// ---------------- RoPE (separate pass): proj fp16 [2048][3072] cols 0..2559 -> qb, kb ----------------
__global__ void rope_kernel(const fp16* __restrict__ proj, fp16* __restrict__ qb, fp16* __restrict__ kb) {
    int tid = blockIdx.x * 256 + threadIdx.x;  // 40*2048*32
    int pair = tid & 31;
    int s = (tid >> 5) & 2047;
    int head = tid >> 16;
    const fp16* src = proj + (size_t)s * 3072 + head * HD + 2 * pair;
    float x1 = (float)src[0];
    float x2 = (float)src[1];
    float invf = expf(-((float)pair / 32.0f) * 9.210340371976184f);  // 10000^(-2j/64)
    float ang = (float)s * invf;
    float sn, cs;
    sincosf(ang, &sn, &cs);
    float o1 = cs * x1 - sn * x2;
    float o2 = sn * x1 + cs * x2;
    fp16* dst = (head < NQH) ? (qb + ((size_t)head * SEQ + s) * HD + 2 * pair)
                             : (kb + ((size_t)(head - NQH) * SEQ + s) * HD + 2 * pair);
    dst[0] = (fp16)o1;
    dst[1] = (fp16)o2;
}

// ---------------- V transpose: proj[s][2560 + g*64 + c] -> vtb[g][c][s] ----------------
__global__ void transpose_v(const fp16* __restrict__ proj, fp16* __restrict__ vtb) {
    __shared__ fp16 tile[64][72];
    const int g = blockIdx.z;
    const int s0 = blockIdx.x * 64;
    const int t = threadIdx.x;
#pragma unroll
    for (int i = 0; i < 16; i++) {
        int idx = i * 256 + t;
        int r = idx >> 6, c = idx & 63;
        tile[r][c] = proj[(size_t)(s0 + r) * 3072 + 2560 + g * HD + c];
    }
    __syncthreads();
#pragma unroll
    for (int i = 0; i < 16; i++) {
        int idx = i * 256 + t;
        int cc = idx >> 6, rr = idx & 63;
        vtb[((size_t)g * HD + cc) * SEQ + s0 + rr] = tile[rr][cc];
    }
}

// ============ GEMM core: 128x128 tile, BK=64, DOUBLE-BUFFERED gll staging, XOR swizzle ============
#define GEMM_CORE(A_, Bt_, K_)                                                              \
    __shared__ fp16 As[2][128][64];                                                         \
    __shared__ fp16 Bs[2][128][64];                                                         \
    const int t = threadIdx.x;                                                              \
    const int m0 = blockIdx.x * 128, n0 = blockIdx.y * 128;                                 \
    const int wid = t >> 6, lane = t & 63;                                                  \
    const int wm = (wid >> 1) * 64, wn = (wid & 1) * 64;                                    \
    const int lr = lane & 15, lg = lane >> 4;                                               \
    f32x4 acc[4][4] = {};                                                                   \
    const int nk = (K_) >> 6;                                                               \
    auto stage_ = [&](int kt, int b) {                                                      \
        _Pragma("unroll") for (int i = 0; i < 4; i++) {                                     \
            int s = i * 256 + t;                                                            \
            int row = s >> 3, ch = s & 7;                                                   \
            int lch = ch ^ (row & 7); /* pre-swizzled global source, linear LDS dest */     \
            gll16((A_) + (size_t)(m0 + row) * (K_) + (kt << 6) + lch * 8,                   \
                  (char*)&As[b][0][0] + s * 16);                                            \
            gll16((Bt_) + (size_t)(n0 + row) * (K_) + (kt << 6) + lch * 8,                  \
                  (char*)&Bs[b][0][0] + s * 16);                                            \
        }                                                                                   \
    };                                                                                      \
    stage_(0, 0);                                                                           \
    __syncthreads();                                                                        \
    for (int kt = 0; kt < nk; ++kt) {                                                       \
        const int cur = kt & 1;                                                             \
        if (kt + 1 < nk) stage_(kt + 1, cur ^ 1);                                           \
        _Pragma("unroll") for (int kk = 0; kk < 2; kk++) {                                  \
            half8 af[4], bfv[4];                                                            \
            _Pragma("unroll") for (int m = 0; m < 4; m++) {                                 \
                int row = wm + m * 16 + lr;                                                 \
                af[m] = *(const half8*)((const char*)&As[cur][row][0] + (((kk * 4 + lg) ^ (row & 7)) * 16)); \
            }                                                                               \
            _Pragma("unroll") for (int n = 0; n < 4; n++) {                                 \
                int row = wn + n * 16 + lr;                                                 \
                bfv[n] = *(const half8*)((const char*)&Bs[cur][row][0] + (((kk * 4 + lg) ^ (row & 7)) * 16)); \
            }                                                                               \
            __builtin_amdgcn_s_setprio(1);                                                  \
            _Pragma("unroll") for (int m = 0; m < 4; m++)                                   \
                _Pragma("unroll") for (int n = 0; n < 4; n++)                               \
                    acc[m][n] = __builtin_amdgcn_mfma_f32_16x16x32_f16(af[m], bfv[n], acc[m][n], 0, 0, 0); \
            __builtin_amdgcn_s_setprio(0);                                                  \
        }                                                                                   \
        __syncthreads(); /* vmcnt drained here -> next tile ready; protects buf reuse */    \
    }

// ---------------- QKV projection: proj[2048][3072] fp16, trivial epilogue ----------------
__global__ __launch_bounds__(256) void gemm_proj(
    const fp16* __restrict__ A, const fp16* __restrict__ Bt, fp16* __restrict__ Cout) {
    GEMM_CORE(A, Bt, 2048)
#pragma unroll
    for (int m = 0; m < 4; m++)
#pragma unroll
        for (int n = 0; n < 4; n++)
#pragma unroll
            for (int r = 0; r < 4; r++) {
                int row = m0 + wm + m * 16 + lg * 4 + r;
                int col = n0 + wn + n * 16 + lr;
                Cout[(size_t)row * 3072 + col] = (fp16)acc[m][n][r];
            }
}

// ---------------- out projection: C[2048][2048] fp32 ----------------
__global__ __launch_bounds__(256) void gemm_out2(
    const fp16* __restrict__ A, const fp16* __restrict__ Bt, float* __restrict__ Cout) {
    GEMM_CORE(A, Bt, 2048)
#pragma unroll
    for (int m = 0; m < 4; m++)
#pragma unroll
        for (int n = 0; n < 4; n++)
#pragma unroll
            for (int r = 0; r < 4; r++) {
                int row = m0 + wm + m * 16 + lg * 4 + r;
                int col = n0 + wn + n * 16 + lr;
                Cout[(size_t)row * 2048 + col] = acc[m][n][r];
            }
}

// ---------------- causal flash attention: 2 heads (same group) per block ----------------
// grid (32, 16): qt = 31 - bx (heaviest first); by -> group g = by>>1, heads h0 = g*4+(by&1)*2, +1.
// 256 thr = 4 waves, each owns 16 q rows of both heads; K/V staged once, two softmax streams.
__global__ __launch_bounds__(256) void attn_kernel(
    const fp16* __restrict__ qb, const fp16* __restrict__ kb,
    const fp16* __restrict__ vt, fp16* __restrict__ o_all) {
    __shared__ fp16 Kb[2][64][64];     // [buf][kv row][dim]   (16B-chunk XOR swizzled)
    __shared__ fp16 Vb[2][64][64];     // [buf][dim][kv-local] (swizzled)
    __shared__ fp16 P[2][4][16][72];   // [head][wave][qrow][kv]
    const int t = threadIdx.x, wid = t >> 6, lane = t & 63;
    const int qt = 31 - (int)blockIdx.x;
    const int by = blockIdx.y;
    const int g = by >> 1;
    const int h0 = g * 4 + (by & 1) * 2;  // heads h0, h0+1
    const int lr = lane & 15, lg = lane >> 4;
    const fp16* kh = kb + (size_t)g * SEQ * HD;
    const fp16* vh = vt + (size_t)g * HD * SEQ;
    const int srow = lane >> 3;   // 0..7
    const int schunk = lane & 7;  // 16B chunk 0..7
    const int qr0 = qt * 64 + wid * 16;

    half8 aq[2][2];
#pragma unroll
    for (int h = 0; h < 2; h++) {
        const fp16* qh = qb + (size_t)(h0 + h) * SEQ * HD;
        aq[h][0] = *reinterpret_cast<const half8*>(qh + (size_t)(qr0 + lr) * HD + lg * 8);
        aq[h][1] = *reinterpret_cast<const half8*>(qh + (size_t)(qr0 + lr) * HD + 32 + lg * 8);
#pragma unroll
        for (int e = 0; e < 8; e++) {  // fold 1/8 score scale into Q (exact: pow2)
            aq[h][0][e] *= (fp16)0.125f;
            aq[h][1][e] *= (fp16)0.125f;
        }
    }
    f32x4 o[2][4] = {};
    float m[2][4], lsum[2][4];  // lsum lane-partial until the end
#pragma unroll
    for (int h = 0; h < 2; h++)
#pragma unroll
        for (int r = 0; r < 4; r++) { m[h][r] = -1e30f; lsum[h][r] = 0.0f; }
    const int nt = qt + 1;

    auto stage = [&](int kt, int b) {
        const int kv0 = kt << 6;
#pragma unroll
        for (int i = 0; i < 2; ++i) {
            int row = wid * 16 + i * 8 + srow;
            int sw = (schunk ^ srow) * 8;
            gll16(kh + (size_t)(kv0 + row) * HD + sw, &Kb[b][wid * 16 + i * 8][0]);
            gll16(vh + (size_t)row * SEQ + kv0 + sw, &Vb[b][wid * 16 + i * 8][0]);
        }
    };

    stage(0, 0);
    __syncthreads();
    for (int tt = 0; tt < nt; ++tt) {
        const int cur = tt & 1;
        if (tt + 1 < nt) stage(tt + 1, cur ^ 1);
        const int kv0 = tt << 6;
        f32x4 sc[2][4];
        __builtin_amdgcn_s_setprio(1);
#pragma unroll
        for (int f = 0; f < 4; ++f) {
            int row = f * 16 + lr;
            const char* kbp = (const char*)&Kb[cur][row][0];
            half8 b0 = *(const half8*)(kbp + (((lg) ^ (row & 7)) * 16));
            half8 b1 = *(const half8*)(kbp + (((4 + lg) ^ (row & 7)) * 16));
#pragma unroll
            for (int h = 0; h < 2; h++) {
                f32x4 s = {};
                s = __builtin_amdgcn_mfma_f32_16x16x32_f16(aq[h][0], b0, s, 0, 0, 0);
                s = __builtin_amdgcn_mfma_f32_16x16x32_f16(aq[h][1], b1, s, 0, 0, 0);
                sc[h][f] = s;
            }
        }
        __builtin_amdgcn_s_setprio(0);
        if (tt == qt) {
#pragma unroll
            for (int f = 0; f < 4; f++)
#pragma unroll
                for (int r = 0; r < 4; r++) {
                    int q = qr0 + lg * 4 + r, kv = kv0 + f * 16 + lr;
                    if (kv > q) { sc[0][f][r] = -1e30f; sc[1][f][r] = -1e30f; }
                }
        }
        // ---- defer-max (both heads share the branch; per-head state) ----
        float lmax[2][4];
        bool ok = true;
#pragma unroll
        for (int h = 0; h < 2; h++)
#pragma unroll
            for (int r = 0; r < 4; r++) {
                lmax[h][r] = fmaxf(fmaxf(sc[h][0][r], sc[h][1][r]), fmaxf(sc[h][2][r], sc[h][3][r]));
                ok = ok && (lmax[h][r] <= m[h][r] + 8.0f);
            }
        if (!__all(ok)) {
#pragma unroll
            for (int h = 0; h < 2; h++)
#pragma unroll
                for (int r = 0; r < 4; r++) {
                    float v = lmax[h][r];
                    v = fmaxf(v, __shfl_xor(v, 1));
                    v = fmaxf(v, __shfl_xor(v, 2));
                    v = fmaxf(v, __shfl_xor(v, 4));
                    v = fmaxf(v, __shfl_xor(v, 8));
                    float mn = fmaxf(m[h][r], v);
                    float alpha = __expf(m[h][r] - mn);
                    m[h][r] = mn;
                    lsum[h][r] *= alpha;
#pragma unroll
                    for (int vf = 0; vf < 4; vf++) o[h][vf][r] *= alpha;
                }
        }
#pragma unroll
        for (int h = 0; h < 2; h++)
#pragma unroll
            for (int f = 0; f < 4; f++)
#pragma unroll
                for (int r = 0; r < 4; r++) {
                    float p = __expf(sc[h][f][r] - m[h][r]);  // bounded by e^8
                    sc[h][f][r] = p;
                    lsum[h][r] += p;
                }
#pragma unroll
        for (int h = 0; h < 2; h++)
#pragma unroll
            for (int f = 0; f < 4; f++)
#pragma unroll
                for (int r = 0; r < 4; r++)
                    P[h][wid][lg * 4 + r][f * 16 + lr] = (fp16)sc[h][f][r];
        __builtin_amdgcn_s_setprio(1);
#pragma unroll
        for (int half = 0; half < 2; half++) {
#pragma unroll
            for (int vf = 0; vf < 4; vf++) {
                int d = vf * 16 + lr;
                int xo = ((half * 4 + lg) ^ (d & 7)) * 16;
                half8 bv = *(const half8*)((const char*)&Vb[cur][d][0] + xo);
#pragma unroll
                for (int h = 0; h < 2; h++) {
                    half8 pa = *reinterpret_cast<const half8*>(&P[h][wid][lr][half * 32 + lg * 8]);
                    o[h][vf] = __builtin_amdgcn_mfma_f32_16x16x32_f16(pa, bv, o[h][vf], 0, 0, 0);
                }
            }
        }
        __builtin_amdgcn_s_setprio(0);
        __syncthreads();  // drains vmcnt (stage of tt+1) + protects buffer reuse
    }
    // final row-sum reduce (once)
#pragma unroll
    for (int h = 0; h < 2; h++)
#pragma unroll
        for (int r = 0; r < 4; r++) {
            float v = lsum[h][r];
            v += __shfl_xor(v, 1);
            v += __shfl_xor(v, 2);
            v += __shfl_xor(v, 4);
            v += __shfl_xor(v, 8);
            lsum[h][r] = v;
        }
#pragma unroll
    for (int h = 0; h < 2; h++)
#pragma unroll
        for (int vf = 0; vf < 4; vf++)
#pragma unroll
            for (int r = 0; r < 4; r++) {
                float v = o[h][vf][r] / lsum[h][r];
                o_all[(size_t)(qr0 + lg * 4 + r) * 2048 + (h0 + h) * 64 + vf * 16 + lr] = (fp16)v;
            }
}

extern "C" void kernel_launch(void* const* d_in, const int* in_sizes, int n_in,
                              void* d_out, int out_size, void* d_ws, size_t ws_size,
                              hipStream_t stream) {
    const float* x  = (const float*)d_in[0];
    const float* wq = (const float*)d_in[1];
    const float* wk = (const float*)d_in[2];
    const float* wv = (const float*)d_in[3];
    const float* wo = (const float*)d_in[4];
    float* out = (float*)d_out;
    char* ws = (char*)d_ws;

    // Workspace (44 MB peak). Aliases: w2t reuses xh (dead after gemm_proj);
    // o_all reuses proj (dead after rope/transpose_v).
    fp16* xh    = (fp16*)(ws);                        // 8 MB [2048][2048]
    fp16* w2t   = xh;                                 // alias
    fp16* wqkvt = (fp16*)(ws + ((size_t)8 << 20));    // 12 MB [3072][2048]
    fp16* proj  = (fp16*)(ws + ((size_t)20 << 20));   // 12 MB [2048][3072]
    fp16* o_all = proj;                               // alias (8 MB)
    fp16* qbuf  = (fp16*)(ws + ((size_t)32 << 20));   // 8 MB [32][2048][64]
    fp16* kbuf  = (fp16*)(ws + ((size_t)40 << 20));   // 2 MB [8][2048][64]
    fp16* vtb   = (fp16*)(ws + ((size_t)42 << 20));   // 2 MB [8][64][2048]

    cast_f32_f16<<<dim3(4096), 256, 0, stream>>>(x, xh, SEQ * DIMM);
    transpose_cast<<<dim3(32, 1, 32), 256, 0, stream>>>(wq, wqkvt, 2048, 64);
    transpose_cast<<<dim3(32, 1, 8), 256, 0, stream>>>(wk, wqkvt + (size_t)32 * 64 * 2048, 2048, 64);
    transpose_cast<<<dim3(32, 1, 8), 256, 0, stream>>>(wv, wqkvt + (size_t)40 * 64 * 2048, 2048, 64);
    gemm_proj<<<dim3(16, 24), 256, 0, stream>>>(xh, wqkvt, proj);
    rope_kernel<<<dim3(10240), 256, 0, stream>>>(proj, qbuf, kbuf);
    transpose_v<<<dim3(32, 1, 8), 256, 0, stream>>>(proj, vtb);
    transpose_cast<<<dim3(32, 32, 1), 256, 0, stream>>>(wo, w2t, 2048, 2048);
    attn_kernel<<<dim3(32, 16), 256, 0, stream>>>(qbuf, kbuf, vtb, o_all);
    gemm_out2<<<dim3(16, 16), 256, 0, stream>>>(o_all, w2t, out);
}

// Round 9
// 174.974 us; speedup vs baseline: 1.1865x; 1.1865x over previous
//
#include <hip/hip_runtime.h>
#include <hip/hip_bf16.h>

#define SEQ 2048
#define DIMM 2048
#define NQH 32
#define NKVH 8
#define HD 64

typedef _Float16 half8 __attribute__((ext_vector_type(8)));
typedef float f32x4 __attribute__((ext_vector_type(4)));
using fp16 = _Float16;

typedef __attribute__((address_space(1))) unsigned int ga_u32;
typedef __attribute__((address_space(3))) unsigned int ls_u32;

__device__ __forceinline__ void gll16(const void* g, void* l) {
    __builtin_amdgcn_global_load_lds((const ga_u32*)g, (ls_u32*)l, 16, 0, 0);
}

// ---------------- cast fp32 -> fp16 (vectorized) ----------------
__global__ void cast_f32_f16(const float* __restrict__ in, fp16* __restrict__ out, int n) {
    int i = (blockIdx.x * 256 + threadIdx.x) * 4;
    if (i < n) {
        float4 v = *reinterpret_cast<const float4*>(in + i);
#pragma unroll
        for (int j = 0; j < 4; j++) out[i + j] = (fp16)(&v.x)[j];
    }
}

// ------------- fused weight transpose: wq/wk/wv fp32 [head][2048][64] -> wqkvt fp16 [48][64][2048] -------------
__global__ void transpose_qkvw(const float* __restrict__ wq, const float* __restrict__ wk,
                               const float* __restrict__ wv, fp16* __restrict__ out) {
    __shared__ float tile[64][65];
    const int z = blockIdx.z;
    const float* inh = (z < 32) ? wq + (size_t)z * SEQ * HD
                                : (z < 40) ? wk + (size_t)(z - 32) * SEQ * HD
                                           : wv + (size_t)(z - 40) * SEQ * HD;
    fp16* outh = out + (size_t)z * HD * SEQ;
    int r0 = blockIdx.x * 64;
    int t = threadIdx.x;
#pragma unroll
    for (int i = 0; i < 16; i++) {
        int idx = i * 256 + t;
        int r = idx >> 6, c = idx & 63;
        tile[r][c] = inh[(size_t)(r0 + r) * HD + c];
    }
    __syncthreads();
#pragma unroll
    for (int i = 0; i < 16; i++) {
        int idx = i * 256 + t;
        int cc = idx >> 6, rr = idx & 63;
        outh[(size_t)cc * SEQ + r0 + rr] = (fp16)tile[rr][cc];
    }
}

// ------------- tiled transpose + cast: in fp32 [R][C] -> out fp16 [C][R] (for w_out) -------------
__global__ void transpose_cast(const float* __restrict__ in, fp16* __restrict__ out, int R, int C) {
    __shared__ float tile[64][65];
    int r0 = blockIdx.x * 64, c0 = blockIdx.y * 64;
    int t = threadIdx.x;
#pragma unroll
    for (int i = 0; i < 16; i++) {
        int idx = i * 256 + t;
        int r = idx >> 6, c = idx & 63;
        tile[r][c] = in[(size_t)(r0 + r) * C + c0 + c];
    }
    __syncthreads();
#pragma unroll
    for (int i = 0; i < 16; i++) {
        int idx = i * 256 + t;
        int cc = idx >> 6, rr = idx & 63;
        out[(size_t)(c0 + cc) * R + r0 + rr] = (fp16)tile[rr][cc];
    }
}

// ---------------- RoPE: proj fp16 [2048][3072] cols 0..2559 -> qb, kb ----------------
__global__ void rope_kernel(const fp16* __restrict__ proj, fp16* __restrict__ qb, fp16* __restrict__ kb) {
    int tid = blockIdx.x * 256 + threadIdx.x;  // 40*2048*32
    int pair = tid & 31;
    int s = (tid >> 5) & 2047;
    int head = tid >> 16;
    const fp16* src = proj + (size_t)s * 3072 + head * HD + 2 * pair;
    float x1 = (float)src[0];
    float x2 = (float)src[1];
    float invf = expf(-((float)pair / 32.0f) * 9.210340371976184f);  // 10000^(-2j/64)
    float ang = (float)s * invf;
    float sn, cs;
    sincosf(ang, &sn, &cs);
    float o1 = cs * x1 - sn * x2;
    float o2 = sn * x1 + cs * x2;
    fp16* dst = (head < NQH) ? (qb + ((size_t)head * SEQ + s) * HD + 2 * pair)
                             : (kb + ((size_t)(head - NQH) * SEQ + s) * HD + 2 * pair);
    dst[0] = (fp16)o1;
    dst[1] = (fp16)o2;
}

// ---------------- V transpose: proj[s][2560 + g*64 + c] -> vtb[g][c][s] ----------------
__global__ void transpose_v(const fp16* __restrict__ proj, fp16* __restrict__ vtb) {
    __shared__ fp16 tile[64][72];
    const int g = blockIdx.z;
    const int s0 = blockIdx.x * 64;
    const int t = threadIdx.x;
#pragma unroll
    for (int i = 0; i < 16; i++) {
        int idx = i * 256 + t;
        int r = idx >> 6, c = idx & 63;
        tile[r][c] = proj[(size_t)(s0 + r) * 3072 + 2560 + g * HD + c];
    }
    __syncthreads();
#pragma unroll
    for (int i = 0; i < 16; i++) {
        int idx = i * 256 + t;
        int cc = idx >> 6, rr = idx & 63;
        vtb[((size_t)g * HD + cc) * SEQ + s0 + rr] = tile[rr][cc];
    }
}

// ============ GEMM core: 128x128 tile, BK=64, DOUBLE-BUFFERED gll staging, XOR swizzle ============
#define GEMM_CORE(A_, Bt_, K_)                                                              \
    __shared__ fp16 As[2][128][64];                                                         \
    __shared__ fp16 Bs[2][128][64];                                                         \
    const int t = threadIdx.x;                                                              \
    const int m0 = blockIdx.x * 128, n0 = blockIdx.y * 128;                                 \
    const int wid = t >> 6, lane = t & 63;                                                  \
    const int wm = (wid >> 1) * 64, wn = (wid & 1) * 64;                                    \
    const int lr = lane & 15, lg = lane >> 4;                                               \
    f32x4 acc[4][4] = {};                                                                   \
    const int nk = (K_) >> 6;                                                               \
    auto stage_ = [&](int kt, int b) {                                                      \
        _Pragma("unroll") for (int i = 0; i < 4; i++) {                                     \
            int s = i * 256 + t;                                                            \
            int row = s >> 3, ch = s & 7;                                                   \
            int lch = ch ^ (row & 7); /* pre-swizzled global source, linear LDS dest */     \
            gll16((A_) + (size_t)(m0 + row) * (K_) + (kt << 6) + lch * 8,                   \
                  (char*)&As[b][0][0] + s * 16);                                            \
            gll16((Bt_) + (size_t)(n0 + row) * (K_) + (kt << 6) + lch * 8,                  \
                  (char*)&Bs[b][0][0] + s * 16);                                            \
        }                                                                                   \
    };                                                                                      \
    stage_(0, 0);                                                                           \
    __syncthreads();                                                                        \
    for (int kt = 0; kt < nk; ++kt) {                                                       \
        const int cur = kt & 1;                                                             \
        if (kt + 1 < nk) stage_(kt + 1, cur ^ 1);                                           \
        _Pragma("unroll") for (int kk = 0; kk < 2; kk++) {                                  \
            half8 af[4], bfv[4];                                                            \
            _Pragma("unroll") for (int m = 0; m < 4; m++) {                                 \
                int row = wm + m * 16 + lr;                                                 \
                af[m] = *(const half8*)((const char*)&As[cur][row][0] + (((kk * 4 + lg) ^ (row & 7)) * 16)); \
            }                                                                               \
            _Pragma("unroll") for (int n = 0; n < 4; n++) {                                 \
                int row = wn + n * 16 + lr;                                                 \
                bfv[n] = *(const half8*)((const char*)&Bs[cur][row][0] + (((kk * 4 + lg) ^ (row & 7)) * 16)); \
            }                                                                               \
            __builtin_amdgcn_s_setprio(1);                                                  \
            _Pragma("unroll") for (int m = 0; m < 4; m++)                                   \
                _Pragma("unroll") for (int n = 0; n < 4; n++)                               \
                    acc[m][n] = __builtin_amdgcn_mfma_f32_16x16x32_f16(af[m], bfv[n], acc[m][n], 0, 0, 0); \
            __builtin_amdgcn_s_setprio(0);                                                  \
        }                                                                                   \
        __syncthreads(); /* vmcnt drained here -> next tile ready; protects buf reuse */    \
    }

// ---------------- QKV projection: proj[2048][3072] fp16, trivial epilogue ----------------
__global__ __launch_bounds__(256) void gemm_proj(
    const fp16* __restrict__ A, const fp16* __restrict__ Bt, fp16* __restrict__ Cout) {
    GEMM_CORE(A, Bt, 2048)
#pragma unroll
    for (int m = 0; m < 4; m++)
#pragma unroll
        for (int n = 0; n < 4; n++)
#pragma unroll
            for (int r = 0; r < 4; r++) {
                int row = m0 + wm + m * 16 + lg * 4 + r;
                int col = n0 + wn + n * 16 + lr;
                Cout[(size_t)row * 3072 + col] = (fp16)acc[m][n][r];
            }
}

// ---------------- out projection: C[2048][2048] fp32 ----------------
__global__ __launch_bounds__(256) void gemm_out2(
    const fp16* __restrict__ A, const fp16* __restrict__ Bt, float* __restrict__ Cout) {
    GEMM_CORE(A, Bt, 2048)
#pragma unroll
    for (int m = 0; m < 4; m++)
#pragma unroll
        for (int n = 0; n < 4; n++)
#pragma unroll
            for (int r = 0; r < 4; r++) {
                int row = m0 + wm + m * 16 + lg * 4 + r;
                int col = n0 + wn + n * 16 + lr;
                Cout[(size_t)row * 2048 + col] = acc[m][n][r];
            }
}

// ---------------- causal flash attention: cross-tile pipelined (QK(t+1) || softmax(t)+PV(t)) ----------------
// grid (16 qpairs, 32 heads), 256 thr = 4 waves; block processes q-tile p then 31-p (33 kv-tiles).
// 3 LDS buffers: stage(t+2) at top of iter t; QK(t+1) issued before softmax(t) for MFMA/VALU overlap.
__global__ __launch_bounds__(256) void attn_kernel(
    const fp16* __restrict__ qb, const fp16* __restrict__ kb,
    const fp16* __restrict__ vt, fp16* __restrict__ o_all) {
    __shared__ fp16 Kb[3][64][64];  // [buf][kv row][dim]   (16B-chunk XOR swizzled)
    __shared__ fp16 Vb[3][64][64];  // [buf][dim][kv-local] (swizzled)
    __shared__ fp16 P[4][16][72];
    const int t = threadIdx.x, wid = t >> 6, lane = t & 63;
    const int head = blockIdx.y, g = head >> 2;
    const int lr = lane & 15, lg = lane >> 4;
    const fp16* qh = qb + (size_t)head * SEQ * HD;
    const fp16* kh = kb + (size_t)g * SEQ * HD;
    const fp16* vh = vt + (size_t)g * HD * SEQ;
    const int srow = lane >> 3;   // 0..7
    const int schunk = lane & 7;  // 16B chunk 0..7

    for (int pass = 0; pass < 2; ++pass) {
        const int qt = (pass == 0) ? (int)blockIdx.x : 31 - (int)blockIdx.x;
        const int qr0 = qt * 64 + wid * 16;
        half8 aq0 = *reinterpret_cast<const half8*>(qh + (size_t)(qr0 + lr) * HD + lg * 8);
        half8 aq1 = *reinterpret_cast<const half8*>(qh + (size_t)(qr0 + lr) * HD + 32 + lg * 8);
#pragma unroll
        for (int e = 0; e < 8; e++) {  // fold 1/8 score scale into Q (exact: pow2)
            aq0[e] *= (fp16)0.125f;
            aq1[e] *= (fp16)0.125f;
        }
        f32x4 o[4] = {};
        float m[4], lsum[4];  // lsum lane-partial until end of pass
#pragma unroll
        for (int r = 0; r < 4; r++) { m[r] = -1e30f; lsum[r] = 0.0f; }
        const int nt = qt + 1;

        auto stage = [&](int kt, int b) {
            const int kv0 = kt << 6;
#pragma unroll
            for (int i = 0; i < 2; ++i) {
                int row = wid * 16 + i * 8 + srow;
                int sw = (schunk ^ srow) * 8;
                gll16(kh + (size_t)(kv0 + row) * HD + sw, &Kb[b][wid * 16 + i * 8][0]);
                gll16(vh + (size_t)row * SEQ + kv0 + sw, &Vb[b][wid * 16 + i * 8][0]);
            }
        };
        // QK^T of tile `tile` from Kb[b3] into dst (scaled Q already)
        auto qkt = [&](f32x4 (&dst)[4], int b3) {
            __builtin_amdgcn_s_setprio(1);
#pragma unroll
            for (int f = 0; f < 4; ++f) {
                int row = f * 16 + lr;
                const char* kbp = (const char*)&Kb[b3][row][0];
                half8 b0 = *(const half8*)(kbp + (((lg) ^ (row & 7)) * 16));
                half8 b1 = *(const half8*)(kbp + (((4 + lg) ^ (row & 7)) * 16));
                f32x4 s = {};
                s = __builtin_amdgcn_mfma_f32_16x16x32_f16(aq0, b0, s, 0, 0, 0);
                s = __builtin_amdgcn_mfma_f32_16x16x32_f16(aq1, b1, s, 0, 0, 0);
                dst[f] = s;
            }
            __builtin_amdgcn_s_setprio(0);
        };
        // softmax(t) on cur + PV(t); QK(t+1) into nxt issued FIRST (pipelined)
        auto body = [&](f32x4 (&cur)[4], f32x4 (&nxt)[4], int tt, int c3, int n3, int s3) {
            if (tt + 2 < nt) stage(tt + 2, s3);
            if (tt + 1 < nt) qkt(nxt, n3);
            if (tt == qt) {
                const int kv0 = tt << 6;
#pragma unroll
                for (int f = 0; f < 4; f++)
#pragma unroll
                    for (int r = 0; r < 4; r++) {
                        int q = qr0 + lg * 4 + r, kv = kv0 + f * 16 + lr;
                        if (kv > q) cur[f][r] = -1e30f;
                    }
            }
            // defer-max: lane-local check; rescale only if some row grew past m+8
            float lmax[4];
            bool ok = true;
#pragma unroll
            for (int r = 0; r < 4; r++) {
                lmax[r] = fmaxf(fmaxf(cur[0][r], cur[1][r]), fmaxf(cur[2][r], cur[3][r]));
                ok = ok && (lmax[r] <= m[r] + 8.0f);
            }
            if (!__all(ok)) {
#pragma unroll
                for (int r = 0; r < 4; r++) {
                    float v = lmax[r];
                    v = fmaxf(v, __shfl_xor(v, 1));
                    v = fmaxf(v, __shfl_xor(v, 2));
                    v = fmaxf(v, __shfl_xor(v, 4));
                    v = fmaxf(v, __shfl_xor(v, 8));
                    float mn = fmaxf(m[r], v);
                    float alpha = __expf(m[r] - mn);
                    m[r] = mn;
                    lsum[r] *= alpha;
#pragma unroll
                    for (int vf = 0; vf < 4; vf++) o[vf][r] *= alpha;
                }
            }
#pragma unroll
            for (int f = 0; f < 4; f++)
#pragma unroll
                for (int r = 0; r < 4; r++) {
                    float p = __expf(cur[f][r] - m[r]);  // bounded by e^8
                    cur[f][r] = p;
                    lsum[r] += p;
                }
#pragma unroll
            for (int f = 0; f < 4; f++)
#pragma unroll
                for (int r = 0; r < 4; r++)
                    P[wid][lg * 4 + r][f * 16 + lr] = (fp16)cur[f][r];
            __builtin_amdgcn_s_setprio(1);
#pragma unroll
            for (int half = 0; half < 2; half++) {
                half8 pa = *reinterpret_cast<const half8*>(&P[wid][lr][half * 32 + lg * 8]);
#pragma unroll
                for (int vf = 0; vf < 4; vf++) {
                    int d = vf * 16 + lr;
                    int xo = ((half * 4 + lg) ^ (d & 7)) * 16;
                    half8 bv = *(const half8*)((const char*)&Vb[c3][d][0] + xo);
                    o[vf] = __builtin_amdgcn_mfma_f32_16x16x32_f16(pa, bv, o[vf], 0, 0, 0);
                }
            }
            __builtin_amdgcn_s_setprio(0);
            __syncthreads();  // drains vmcnt (stage of tt+2) + protects buffer reuse
        };

        // prologue: stage tiles 0,1; compute QK(0)
        stage(0, 0);
        stage(1, 1);  // tile 1 always within SEQ bounds (harmless if nt==1)
        __syncthreads();
        f32x4 scA[4], scB[4];
        qkt(scA, 0);
        int c3 = 0;
        for (int tt = 0; tt < nt; ++tt) {
            int n3 = c3 + 1; if (n3 == 3) n3 = 0;
            int s3 = n3 + 1; if (s3 == 3) s3 = 0;
            if ((tt & 1) == 0) body(scA, scB, tt, c3, n3, s3);
            else               body(scB, scA, tt, c3, n3, s3);
            c3 = n3;
        }
        // final row-sum reduce (once per pass)
#pragma unroll
        for (int r = 0; r < 4; r++) {
            float v = lsum[r];
            v += __shfl_xor(v, 1);
            v += __shfl_xor(v, 2);
            v += __shfl_xor(v, 4);
            v += __shfl_xor(v, 8);
            lsum[r] = v;
        }
#pragma unroll
        for (int vf = 0; vf < 4; vf++)
#pragma unroll
            for (int r = 0; r < 4; r++) {
                float v = o[vf][r] / lsum[r];
                o_all[(size_t)(qr0 + lg * 4 + r) * 2048 + head * 64 + vf * 16 + lr] = (fp16)v;
            }
        __syncthreads();  // pass boundary: all reads done before next pass restages
    }
}

extern "C" void kernel_launch(void* const* d_in, const int* in_sizes, int n_in,
                              void* d_out, int out_size, void* d_ws, size_t ws_size,
                              hipStream_t stream) {
    const float* x  = (const float*)d_in[0];
    const float* wq = (const float*)d_in[1];
    const float* wk = (const float*)d_in[2];
    const float* wv = (const float*)d_in[3];
    const float* wo = (const float*)d_in[4];
    float* out = (float*)d_out;
    char* ws = (char*)d_ws;

    // Workspace (44 MB peak). Aliases: w2t reuses xh (dead after gemm_proj);
    // o_all reuses proj (dead after rope/transpose_v).
    fp16* xh    = (fp16*)(ws);                        // 8 MB [2048][2048]
    fp16* w2t   = xh;                                 // alias
    fp16* wqkvt = (fp16*)(ws + ((size_t)8 << 20));    // 12 MB [3072][2048] ([48][64][2048])
    fp16* proj  = (fp16*)(ws + ((size_t)20 << 20));   // 12 MB [2048][3072]
    fp16* o_all = proj;                               // alias (8 MB)
    fp16* qbuf  = (fp16*)(ws + ((size_t)32 << 20));   // 8 MB [32][2048][64]
    fp16* kbuf  = (fp16*)(ws + ((size_t)40 << 20));   // 2 MB [8][2048][64]
    fp16* vtb   = (fp16*)(ws + ((size_t)42 << 20));   // 2 MB [8][64][2048]

    cast_f32_f16<<<dim3(4096), 256, 0, stream>>>(x, xh, SEQ * DIMM);
    transpose_qkvw<<<dim3(32, 1, 48), 256, 0, stream>>>(wq, wk, wv, wqkvt);
    gemm_proj<<<dim3(16, 24), 256, 0, stream>>>(xh, wqkvt, proj);
    rope_kernel<<<dim3(10240), 256, 0, stream>>>(proj, qbuf, kbuf);
    transpose_v<<<dim3(32, 1, 8), 256, 0, stream>>>(proj, vtb);
    transpose_cast<<<dim3(32, 32), 256, 0, stream>>>(wo, w2t, 2048, 2048);
    attn_kernel<<<dim3(16, 32), 256, 0, stream>>>(qbuf, kbuf, vtb, o_all);
    gemm_out2<<<dim3(16, 16), 256, 0, stream>>>(o_all, w2t, out);
}

// Round 10
// 159.570 us; speedup vs baseline: 1.3011x; 1.0965x over previous
//
#include <hip/hip_runtime.h>
#include <hip/hip_bf16.h>

#define SEQ 2048
#define DIMM 2048
#define NQH 32
#define NKVH 8
#define HD 64

typedef _Float16 half8 __attribute__((ext_vector_type(8)));
typedef float f32x4 __attribute__((ext_vector_type(4)));
using fp16 = _Float16;

typedef __attribute__((address_space(1))) unsigned int ga_u32;
typedef __attribute__((address_space(3))) unsigned int ls_u32;

__device__ __forceinline__ void gll16(const void* g, void* l) {
    __builtin_amdgcn_global_load_lds((const ga_u32*)g, (ls_u32*)l, 16, 0, 0);
}

// ---------------- cast fp32 -> fp16 (vectorized) ----------------
__global__ void cast_f32_f16(const float* __restrict__ in, fp16* __restrict__ out, int n) {
    int i = (blockIdx.x * 256 + threadIdx.x) * 4;
    if (i < n) {
        float4 v = *reinterpret_cast<const float4*>(in + i);
#pragma unroll
        for (int j = 0; j < 4; j++) out[i + j] = (fp16)(&v.x)[j];
    }
}

// ------------- fused weight transpose: wq/wk/wv fp32 [head][2048][64] -> wqkvt fp16 [48][64][2048] -------------
__global__ void transpose_qkvw(const float* __restrict__ wq, const float* __restrict__ wk,
                               const float* __restrict__ wv, fp16* __restrict__ out) {
    __shared__ float tile[64][65];
    const int z = blockIdx.z;
    const float* inh = (z < 32) ? wq + (size_t)z * SEQ * HD
                                : (z < 40) ? wk + (size_t)(z - 32) * SEQ * HD
                                           : wv + (size_t)(z - 40) * SEQ * HD;
    fp16* outh = out + (size_t)z * HD * SEQ;
    int r0 = blockIdx.x * 64;
    int t = threadIdx.x;
#pragma unroll
    for (int i = 0; i < 16; i++) {
        int idx = i * 256 + t;
        int r = idx >> 6, c = idx & 63;
        tile[r][c] = inh[(size_t)(r0 + r) * HD + c];
    }
    __syncthreads();
#pragma unroll
    for (int i = 0; i < 16; i++) {
        int idx = i * 256 + t;
        int cc = idx >> 6, rr = idx & 63;
        outh[(size_t)cc * SEQ + r0 + rr] = (fp16)tile[rr][cc];
    }
}

// ------------- tiled transpose + cast: in fp32 [R][C] -> out fp16 [C][R] (for w_out) -------------
__global__ void transpose_cast(const float* __restrict__ in, fp16* __restrict__ out, int R, int C) {
    __shared__ float tile[64][65];
    int r0 = blockIdx.x * 64, c0 = blockIdx.y * 64;
    int t = threadIdx.x;
#pragma unroll
    for (int i = 0; i < 16; i++) {
        int idx = i * 256 + t;
        int r = idx >> 6, c = idx & 63;
        tile[r][c] = in[(size_t)(r0 + r) * C + c0 + c];
    }
    __syncthreads();
#pragma unroll
    for (int i = 0; i < 16; i++) {
        int idx = i * 256 + t;
        int cc = idx >> 6, rr = idx & 63;
        out[(size_t)(c0 + cc) * R + r0 + rr] = (fp16)tile[rr][cc];
    }
}

// ---------------- RoPE: proj fp16 [2048][3072] cols 0..2559 -> qb, kb ----------------
__global__ void rope_kernel(const fp16* __restrict__ proj, fp16* __restrict__ qb, fp16* __restrict__ kb) {
    int tid = blockIdx.x * 256 + threadIdx.x;  // 40*2048*32
    int pair = tid & 31;
    int s = (tid >> 5) & 2047;
    int head = tid >> 16;
    const fp16* src = proj + (size_t)s * 3072 + head * HD + 2 * pair;
    float x1 = (float)src[0];
    float x2 = (float)src[1];
    float invf = expf(-((float)pair / 32.0f) * 9.210340371976184f);  // 10000^(-2j/64)
    float ang = (float)s * invf;
    float sn, cs;
    sincosf(ang, &sn, &cs);
    float o1 = cs * x1 - sn * x2;
    float o2 = sn * x1 + cs * x2;
    fp16* dst = (head < NQH) ? (qb + ((size_t)head * SEQ + s) * HD + 2 * pair)
                             : (kb + ((size_t)(head - NQH) * SEQ + s) * HD + 2 * pair);
    dst[0] = (fp16)o1;
    dst[1] = (fp16)o2;
}

// ---------------- V transpose: proj[s][2560 + g*64 + c] -> vtb[g][c][s] ----------------
__global__ void transpose_v(const fp16* __restrict__ proj, fp16* __restrict__ vtb) {
    __shared__ fp16 tile[64][72];
    const int g = blockIdx.z;
    const int s0 = blockIdx.x * 64;
    const int t = threadIdx.x;
#pragma unroll
    for (int i = 0; i < 16; i++) {
        int idx = i * 256 + t;
        int r = idx >> 6, c = idx & 63;
        tile[r][c] = proj[(size_t)(s0 + r) * 3072 + 2560 + g * HD + c];
    }
    __syncthreads();
#pragma unroll
    for (int i = 0; i < 16; i++) {
        int idx = i * 256 + t;
        int cc = idx >> 6, rr = idx & 63;
        vtb[((size_t)g * HD + cc) * SEQ + s0 + rr] = tile[rr][cc];
    }
}

// ============ GEMM core: 128x128 tile, BK=64, DOUBLE-BUFFERED gll staging, XOR swizzle ============
#define GEMM_CORE(A_, Bt_, K_)                                                              \
    __shared__ fp16 As[2][128][64];                                                         \
    __shared__ fp16 Bs[2][128][64];                                                         \
    const int t = threadIdx.x;                                                              \
    const int m0 = blockIdx.x * 128, n0 = blockIdx.y * 128;                                 \
    const int wid = t >> 6, lane = t & 63;                                                  \
    const int wm = (wid >> 1) * 64, wn = (wid & 1) * 64;                                    \
    const int lr = lane & 15, lg = lane >> 4;                                               \
    f32x4 acc[4][4] = {};                                                                   \
    const int nk = (K_) >> 6;                                                               \
    auto stage_ = [&](int kt, int b) {                                                      \
        _Pragma("unroll") for (int i = 0; i < 4; i++) {                                     \
            int s = i * 256 + t;                                                            \
            int row = s >> 3, ch = s & 7;                                                   \
            int lch = ch ^ (row & 7); /* pre-swizzled global source, linear LDS dest */     \
            gll16((A_) + (size_t)(m0 + row) * (K_) + (kt << 6) + lch * 8,                   \
                  (char*)&As[b][0][0] + s * 16);                                            \
            gll16((Bt_) + (size_t)(n0 + row) * (K_) + (kt << 6) + lch * 8,                  \
                  (char*)&Bs[b][0][0] + s * 16);                                            \
        }                                                                                   \
    };                                                                                      \
    stage_(0, 0);                                                                           \
    __syncthreads();                                                                        \
    for (int kt = 0; kt < nk; ++kt) {                                                       \
        const int cur = kt & 1;                                                             \
        if (kt + 1 < nk) stage_(kt + 1, cur ^ 1);                                           \
        _Pragma("unroll") for (int kk = 0; kk < 2; kk++) {                                  \
            half8 af[4], bfv[4];                                                            \
            _Pragma("unroll") for (int m = 0; m < 4; m++) {                                 \
                int row = wm + m * 16 + lr;                                                 \
                af[m] = *(const half8*)((const char*)&As[cur][row][0] + (((kk * 4 + lg) ^ (row & 7)) * 16)); \
            }                                                                               \
            _Pragma("unroll") for (int n = 0; n < 4; n++) {                                 \
                int row = wn + n * 16 + lr;                                                 \
                bfv[n] = *(const half8*)((const char*)&Bs[cur][row][0] + (((kk * 4 + lg) ^ (row & 7)) * 16)); \
            }                                                                               \
            __builtin_amdgcn_s_setprio(1);                                                  \
            _Pragma("unroll") for (int m = 0; m < 4; m++)                                   \
                _Pragma("unroll") for (int n = 0; n < 4; n++)                               \
                    acc[m][n] = __builtin_amdgcn_mfma_f32_16x16x32_f16(af[m], bfv[n], acc[m][n], 0, 0, 0); \
            __builtin_amdgcn_s_setprio(0);                                                  \
        }                                                                                   \
        __syncthreads(); /* vmcnt drained here -> next tile ready; protects buf reuse */    \
    }

// ---------------- QKV projection: proj[2048][3072] fp16, trivial epilogue ----------------
__global__ __launch_bounds__(256) void gemm_proj(
    const fp16* __restrict__ A, const fp16* __restrict__ Bt, fp16* __restrict__ Cout) {
    GEMM_CORE(A, Bt, 2048)
#pragma unroll
    for (int m = 0; m < 4; m++)
#pragma unroll
        for (int n = 0; n < 4; n++)
#pragma unroll
            for (int r = 0; r < 4; r++) {
                int row = m0 + wm + m * 16 + lg * 4 + r;
                int col = n0 + wn + n * 16 + lr;
                Cout[(size_t)row * 3072 + col] = (fp16)acc[m][n][r];
            }
}

// ---------------- out projection: C[2048][2048] fp32 ----------------
__global__ __launch_bounds__(256) void gemm_out2(
    const fp16* __restrict__ A, const fp16* __restrict__ Bt, float* __restrict__ Cout) {
    GEMM_CORE(A, Bt, 2048)
#pragma unroll
    for (int m = 0; m < 4; m++)
#pragma unroll
        for (int n = 0; n < 4; n++)
#pragma unroll
            for (int r = 0; r < 4; r++) {
                int row = m0 + wm + m * 16 + lg * 4 + r;
                int col = n0 + wn + n * 16 + lr;
                Cout[(size_t)row * 2048 + col] = acc[m][n][r];
            }
}

// ---------------- causal flash attention (round-7 body; 1024 blocks, heavy-first) ----------------
// grid (1024): qt = 31 - (bx>>5) so heavy q-tiles dispatch first; head = bx & 31.
// 256 thr = 4 waves; each wave owns 16 q rows; K/V double-buffered in LDS (42 KB -> 3 blocks/CU).
__global__ __launch_bounds__(256) void attn_kernel(
    const fp16* __restrict__ qb, const fp16* __restrict__ kb,
    const fp16* __restrict__ vt, fp16* __restrict__ o_all) {
    __shared__ fp16 Kb[2][64][64];  // [buf][kv row][dim]   (16B-chunk XOR swizzled)
    __shared__ fp16 Vb[2][64][64];  // [buf][dim][kv-local] (swizzled)
    __shared__ fp16 P[4][16][72];
    const int t = threadIdx.x, wid = t >> 6, lane = t & 63;
    const int bx = blockIdx.x;
    const int qt = 31 - (bx >> 5);
    const int head = bx & 31;
    const int g = head >> 2;
    const int lr = lane & 15, lg = lane >> 4;
    const fp16* qh = qb + (size_t)head * SEQ * HD;
    const fp16* kh = kb + (size_t)g * SEQ * HD;
    const fp16* vh = vt + (size_t)g * HD * SEQ;
    const int srow = lane >> 3;   // 0..7
    const int schunk = lane & 7;  // 16B chunk 0..7
    const int qr0 = qt * 64 + wid * 16;

    half8 aq0 = *reinterpret_cast<const half8*>(qh + (size_t)(qr0 + lr) * HD + lg * 8);
    half8 aq1 = *reinterpret_cast<const half8*>(qh + (size_t)(qr0 + lr) * HD + 32 + lg * 8);
#pragma unroll
    for (int e = 0; e < 8; e++) {  // fold 1/8 score scale into Q (exact: pow2)
        aq0[e] *= (fp16)0.125f;
        aq1[e] *= (fp16)0.125f;
    }
    f32x4 o[4] = {};
    float m[4], lsum[4];  // lsum lane-partial until the end
#pragma unroll
    for (int r = 0; r < 4; r++) { m[r] = -1e30f; lsum[r] = 0.0f; }
    const int nt = qt + 1;

    auto stage = [&](int kt, int b) {
        const int kv0 = kt << 6;
#pragma unroll
        for (int i = 0; i < 2; ++i) {
            int row = wid * 16 + i * 8 + srow;
            int sw = (schunk ^ srow) * 8;
            gll16(kh + (size_t)(kv0 + row) * HD + sw, &Kb[b][wid * 16 + i * 8][0]);
            gll16(vh + (size_t)row * SEQ + kv0 + sw, &Vb[b][wid * 16 + i * 8][0]);
        }
    };

    stage(0, 0);
    __syncthreads();
    for (int tt = 0; tt < nt; ++tt) {
        const int cur = tt & 1;
        if (tt + 1 < nt) stage(tt + 1, cur ^ 1);
        const int kv0 = tt << 6;
        f32x4 sc[4];
        __builtin_amdgcn_s_setprio(1);
#pragma unroll
        for (int f = 0; f < 4; ++f) {
            int row = f * 16 + lr;
            const char* kbp = (const char*)&Kb[cur][row][0];
            half8 b0 = *(const half8*)(kbp + (((lg) ^ (row & 7)) * 16));
            half8 b1 = *(const half8*)(kbp + (((4 + lg) ^ (row & 7)) * 16));
            f32x4 s = {};
            s = __builtin_amdgcn_mfma_f32_16x16x32_f16(aq0, b0, s, 0, 0, 0);
            s = __builtin_amdgcn_mfma_f32_16x16x32_f16(aq1, b1, s, 0, 0, 0);
            sc[f] = s;
        }
        __builtin_amdgcn_s_setprio(0);
        if (tt == qt) {
#pragma unroll
            for (int f = 0; f < 4; f++)
#pragma unroll
                for (int r = 0; r < 4; r++) {
                    int q = qr0 + lg * 4 + r, kv = kv0 + f * 16 + lr;
                    if (kv > q) sc[f][r] = -1e30f;
                }
        }
        // ---- defer-max: lane-local check; rescale only if some row grew past m+8 ----
        float lmax[4];
        bool ok = true;
#pragma unroll
        for (int r = 0; r < 4; r++) {
            lmax[r] = fmaxf(fmaxf(sc[0][r], sc[1][r]), fmaxf(sc[2][r], sc[3][r]));
            ok = ok && (lmax[r] <= m[r] + 8.0f);
        }
        if (!__all(ok)) {  // rare path: full cross-lane max + rescale
#pragma unroll
            for (int r = 0; r < 4; r++) {
                float v = lmax[r];
                v = fmaxf(v, __shfl_xor(v, 1));
                v = fmaxf(v, __shfl_xor(v, 2));
                v = fmaxf(v, __shfl_xor(v, 4));
                v = fmaxf(v, __shfl_xor(v, 8));
                float mn = fmaxf(m[r], v);
                float alpha = __expf(m[r] - mn);
                m[r] = mn;
                lsum[r] *= alpha;
#pragma unroll
                for (int vf = 0; vf < 4; vf++) o[vf][r] *= alpha;
            }
        }
#pragma unroll
        for (int f = 0; f < 4; f++)
#pragma unroll
            for (int r = 0; r < 4; r++) {
                float p = __expf(sc[f][r] - m[r]);  // bounded by e^8
                sc[f][r] = p;
                lsum[r] += p;  // lane-partial; reduced once at the end
            }
#pragma unroll
        for (int f = 0; f < 4; f++)
#pragma unroll
            for (int r = 0; r < 4; r++)
                P[wid][lg * 4 + r][f * 16 + lr] = (fp16)sc[f][r];
        __builtin_amdgcn_s_setprio(1);
#pragma unroll
        for (int half = 0; half < 2; half++) {
            half8 pa = *reinterpret_cast<const half8*>(&P[wid][lr][half * 32 + lg * 8]);
#pragma unroll
            for (int vf = 0; vf < 4; vf++) {
                int d = vf * 16 + lr;
                int xo = ((half * 4 + lg) ^ (d & 7)) * 16;
                half8 bv = *(const half8*)((const char*)&Vb[cur][d][0] + xo);
                o[vf] = __builtin_amdgcn_mfma_f32_16x16x32_f16(pa, bv, o[vf], 0, 0, 0);
            }
        }
        __builtin_amdgcn_s_setprio(0);
        __syncthreads();  // drains vmcnt (stage of tt+1) + protects buffer reuse
    }
    // final row-sum reduce (once)
#pragma unroll
    for (int r = 0; r < 4; r++) {
        float v = lsum[r];
        v += __shfl_xor(v, 1);
        v += __shfl_xor(v, 2);
        v += __shfl_xor(v, 4);
        v += __shfl_xor(v, 8);
        lsum[r] = v;
    }
#pragma unroll
    for (int vf = 0; vf < 4; vf++)
#pragma unroll
        for (int r = 0; r < 4; r++) {
            float v = o[vf][r] / lsum[r];
            o_all[(size_t)(qr0 + lg * 4 + r) * 2048 + head * 64 + vf * 16 + lr] = (fp16)v;
        }
}

extern "C" void kernel_launch(void* const* d_in, const int* in_sizes, int n_in,
                              void* d_out, int out_size, void* d_ws, size_t ws_size,
                              hipStream_t stream) {
    const float* x  = (const float*)d_in[0];
    const float* wq = (const float*)d_in[1];
    const float* wk = (const float*)d_in[2];
    const float* wv = (const float*)d_in[3];
    const float* wo = (const float*)d_in[4];
    float* out = (float*)d_out;
    char* ws = (char*)d_ws;

    // Workspace (44 MB peak). Aliases: w2t reuses xh (dead after gemm_proj);
    // o_all reuses proj (dead after rope/transpose_v).
    fp16* xh    = (fp16*)(ws);                        // 8 MB [2048][2048]
    fp16* w2t   = xh;                                 // alias
    fp16* wqkvt = (fp16*)(ws + ((size_t)8 << 20));    // 12 MB [3072][2048] ([48][64][2048])
    fp16* proj  = (fp16*)(ws + ((size_t)20 << 20));   // 12 MB [2048][3072]
    fp16* o_all = proj;                               // alias (8 MB)
    fp16* qbuf  = (fp16*)(ws + ((size_t)32 << 20));   // 8 MB [32][2048][64]
    fp16* kbuf  = (fp16*)(ws + ((size_t)40 << 20));   // 2 MB [8][2048][64]
    fp16* vtb   = (fp16*)(ws + ((size_t)42 << 20));   // 2 MB [8][64][2048]

    cast_f32_f16<<<dim3(4096), 256, 0, stream>>>(x, xh, SEQ * DIMM);
    transpose_qkvw<<<dim3(32, 1, 48), 256, 0, stream>>>(wq, wk, wv, wqkvt);
    gemm_proj<<<dim3(16, 24), 256, 0, stream>>>(xh, wqkvt, proj);
    rope_kernel<<<dim3(10240), 256, 0, stream>>>(proj, qbuf, kbuf);
    transpose_v<<<dim3(32, 1, 8), 256, 0, stream>>>(proj, vtb);
    transpose_cast<<<dim3(32, 32), 256, 0, stream>>>(wo, w2t, 2048, 2048);
    attn_kernel<<<dim3(1024), 256, 0, stream>>>(qbuf, kbuf, vtb, o_all);
    gemm_out2<<<dim3(16, 16), 256, 0, stream>>>(o_all, w2t, out);
}